// Round 7
// baseline (118.599 us; speedup 1.0000x reference)
//
#include <hip/hip_runtime.h>
#include <stdint.h>

// out[b,c] = <x_b/||x_b||, a_c/||a_c||>, B=16384, C=2048, D=1024, fp32 in/out.
// Pass 1: fp32 row-normalize -> bf16 into d_ws (single merged launch).
// Pass 2: bf16 MFMA GEMM, 256x256 tile, 8 waves (2Mx4N), BK=64.
//   R7 design: A-only in LDS (2x32KB double buffer); B fragments loaded
//   DIRECTLY from global (L2-resident: whole B = 4MB/XCD) into registers,
//   per-wave, compiler-managed waits -> no cross-wave coupling for B.
//   ONE barrier + ONE counted vmcnt(8) per K-tile (A buffer swap only).
//   Within a tile the 8 waves free-run: ds_read/MFMA/global-load overlap via
//   wave skew (m114 implicit overlap) instead of hand-scheduled phases.
//   Boundary race proof: per tile, VM issue order is [4 A-stage DMA][SB][8 B
//   loads][SB] (sched_barrier(0) pins order); at boundary vmcnt(8) the 8
//   newest (B) may remain -> all A stages landed; then s_barrier -> all
//   waves' A landed before next tile reads (vmcnt -> barrier -> read rule).
//   A(t+1) DMA targets buf^1, whose tile-(t-1) readers all completed before
//   the t-1 boundary barrier (lgkm waits precede MFMAs precede barrier).

#define D_DIM 1024
#define N_DIM 2048
#define BMt 256
#define BNt 256
#define BKt 64
#define NKT 16      // D_DIM / BKt

typedef __bf16 bf16x8 __attribute__((ext_vector_type(8)));
typedef float  f32x4  __attribute__((ext_vector_type(4)));

__device__ __forceinline__ unsigned short f2bf(float f) {
    union { float f; uint32_t u; } v; v.f = f;
    uint32_t r = v.u + 0x7fffu + ((v.u >> 16) & 1u);  // RNE
    return (unsigned short)(r >> 16);
}

// One block per row (X rows then A rows): 256 threads x float4 = 1024 floats.
__global__ __launch_bounds__(256) void normalize_rows(
        const float* __restrict__ x, const float* __restrict__ a,
        unsigned short* __restrict__ xn, unsigned short* __restrict__ an,
        int Bn) {
    const int blk = blockIdx.x;
    const float* in = (blk < Bn) ? x : a;
    unsigned short* out = (blk < Bn) ? xn : an;
    const int row = (blk < Bn) ? blk : blk - Bn;
    const int t = threadIdx.x;
    const float4 v = ((const float4*)(in + (size_t)row * D_DIM))[t];
    float ss = v.x * v.x + v.y * v.y + v.z * v.z + v.w * v.w;
#pragma unroll
    for (int o = 1; o < 64; o <<= 1) ss += __shfl_xor(ss, o);
    __shared__ float red[4];
    if ((t & 63) == 0) red[t >> 6] = ss;
    __syncthreads();
    const float tot = red[0] + red[1] + red[2] + red[3];
    const float scale = 1.0f / fmaxf(sqrtf(tot), 1e-8f);
    ushort4 o;
    o.x = f2bf(v.x * scale);
    o.y = f2bf(v.y * scale);
    o.z = f2bf(v.z * scale);
    o.w = f2bf(v.w * scale);
    ((ushort4*)(out + (size_t)row * D_DIM))[t] = o;
}

__device__ __forceinline__ void gload_lds16(const void* g, void* l) {
    __builtin_amdgcn_global_load_lds(
        (const __attribute__((address_space(1))) void*)g,
        (__attribute__((address_space(3))) void*)l,
        16, 0, 0);
}

// LDS A-tile: [256 rows][64 K] bf16, 128 B/row, 8 x 16B slots/row.
// Stored slot = logical slot ^ (row & 7)  -> ds_read_b128 conflict-free.
__device__ __forceinline__ bf16x8 lds_frag(const unsigned short* opb, int R, int t) {
    const int byt = R * 128 + ((t ^ (R & 7)) << 4);
    return *(const bf16x8*)((const char*)opb + byt);
}

// Stage one A half-tile (128 rows x 64 K = 16 KB): 2 gload_lds per thread.
// Linear LDS dest; global col pre-swizzled to invert the read swizzle.
__device__ __forceinline__ void stage_half(
        const unsigned short* __restrict__ src, int grow0, int k0,
        unsigned short* dst_region, int tid, int wid) {
    const int gcol = (((tid & 7) ^ ((tid >> 3) & 7)) << 3);
    const int grow = (tid >> 3);
#pragma unroll
    for (int j = 0; j < 2; ++j)
        gload_lds16(&src[(size_t)(grow0 + j * 64 + grow) * D_DIM + k0 + gcol],
                    dst_region + ((size_t)(j * 512 + wid * 64)) * 8);
}

#define SCHED_PIN() __builtin_amdgcn_sched_barrier(0)
#define BOUND_VM8() asm volatile("s_waitcnt vmcnt(8)" ::: "memory")
#define BAR()       asm volatile("s_barrier" ::: "memory")

// MODE 0: steady tile (stage A(t+1), load B(t+1), boundary vmcnt(8)+bar)
// MODE 1: tail t=15 (nothing staged, no boundary)
// MODE 2: t=0 (= MODE 0 + entry wait vmcnt(20)+bar before reads)
template<int MODE>
__device__ __forceinline__ void tile_body(
        int t, const unsigned short* __restrict__ A,
        const unsigned short* __restrict__ Bm, unsigned short* lds,
        int rowA0, int rowB0, int tid, int wid, int wr, int wc,
        bf16x8 (&bcur)[4][2], bf16x8 (&bnxt)[4][2],
        f32x4 (&acc)[8][4])
{
    const int lane = tid & 63;
    const int rl = lane & 15, ts = lane >> 4;
    unsigned short* bufA = lds + ((size_t)(t & 1)) * 16384;        // A(t)
    unsigned short* stA  = lds + ((size_t)((t + 1) & 1)) * 16384;  // A(t+1) dst

    if constexpr (MODE != 1) {
        // [VM order 1] stage A(t+1): 4 gload_lds
        stage_half(A, rowA0 + 0,   (t + 1) * BKt, stA + 0,    tid, wid);
        stage_half(A, rowA0 + 128, (t + 1) * BKt, stA + 8192, tid, wid);
        SCHED_PIN();
        // [VM order 2] load B(t+1) fragments: 8 global_load_dwordx4 (L2-hit)
#pragma unroll
        for (int n = 0; n < 4; ++n)
#pragma unroll
            for (int kk = 0; kk < 2; ++kk)
                bnxt[n][kk] = *(const bf16x8*)&Bm[
                    (size_t)(rowB0 + wc * 64 + n * 16 + rl) * D_DIM
                    + (t + 1) * BKt + kk * 32 + ts * 8];
        SCHED_PIN();
    }
    if constexpr (MODE == 2) {
        // entry: A(0) issued 20 VM ops ago (B0:8, A1:4, B1:8 newer) -> landed
        asm volatile("s_waitcnt vmcnt(20)" ::: "memory");
        BAR();
    }

    // A fragment reads: 16 ds_read_b128 (swizzled, conflict-free)
    bf16x8 af[8][2];
#pragma unroll
    for (int m = 0; m < 8; ++m)
#pragma unroll
        for (int kk = 0; kk < 2; ++kk)
            af[m][kk] = lds_frag(bufA, wr * 128 + m * 16 + rl, kk * 4 + ts);

    // 64 MFMA; compiler inserts precise lgkm/vm waits (free-run, no barriers)
#pragma unroll
    for (int m = 0; m < 8; ++m)
#pragma unroll
        for (int n = 0; n < 4; ++n)
#pragma unroll
            for (int kk = 0; kk < 2; ++kk)
                acc[m][n] = __builtin_amdgcn_mfma_f32_16x16x32_bf16(
                    af[m][kk], bcur[n][kk], acc[m][n], 0, 0, 0);

    if constexpr (MODE != 1) {
        BOUND_VM8();   // newest 8 = B(t+1); all A(t+1) DMA landed
        BAR();         // every wave passed its vmcnt -> next tile may read
    }
}

__global__ __launch_bounds__(512, 2) void gemm256(
        const unsigned short* __restrict__ A,
        const unsigned short* __restrict__ Bm,
        float* __restrict__ Cg)
{
    __shared__ unsigned short lds[32768];  // 64 KiB: 2 x 32KB A buffers

    const int nwg = gridDim.x;          // 512
    const int cpx = nwg >> 3;           // 64
    const int wg  = ((int)blockIdx.x & 7) * cpx + ((int)blockIdx.x >> 3);
    const int bm  = wg >> 3;            // 0..63 (8 consecutive share XCD)
    const int bn  = wg & 7;             // 0..7
    const int rowA0 = bm * BMt;
    const int rowB0 = bn * BNt;

    const int tid  = threadIdx.x;
    const int lane = tid & 63;
    const int wid  = tid >> 6;          // 0..7
    const int wr   = wid >> 2;          // 0..1 -> 128-row half
    const int wc   = wid & 3;           // 0..3 -> 64-col slice
    const int rl = lane & 15, ts = lane >> 4;

    bf16x8 bA[4][2], bB[4][2];
    f32x4 acc[8][4] = {};

    // prologue: [VM 1] stage A(0); [VM 2] load B(0). t=0 body adds A(1), B(1).
    stage_half(A, rowA0 + 0,   0, lds + 0,    tid, wid);
    stage_half(A, rowA0 + 128, 0, lds + 8192, tid, wid);
    SCHED_PIN();
#pragma unroll
    for (int n = 0; n < 4; ++n)
#pragma unroll
        for (int kk = 0; kk < 2; ++kk)
            bA[n][kk] = *(const bf16x8*)&Bm[
                (size_t)(rowB0 + wc * 64 + n * 16 + rl) * D_DIM + kk * 32 + ts * 8];
    SCHED_PIN();

    tile_body<2>(0, A, Bm, lds, rowA0, rowB0, tid, wid, wr, wc, bA, bB, acc);
#pragma unroll 1
    for (int p = 0; p < 7; ++p) {
        tile_body<0>(2 * p + 1, A, Bm, lds, rowA0, rowB0, tid, wid, wr, wc, bB, bA, acc);
        tile_body<0>(2 * p + 2, A, Bm, lds, rowA0, rowB0, tid, wid, wr, wc, bA, bB, acc);
    }
    tile_body<1>(NKT - 1, A, Bm, lds, rowA0, rowB0, tid, wid, wr, wc, bB, bA, acc);

    // epilogue: C/D layout col=lane&15, row=(lane>>4)*4+j (m89-verified)
    const int crow0 = rowA0 + wr * 128 + (lane >> 4) * 4;
    const int ccol0 = rowB0 + wc * 64 + (lane & 15);
#pragma unroll
    for (int m = 0; m < 8; ++m)
#pragma unroll
        for (int n = 0; n < 4; ++n)
#pragma unroll
            for (int j = 0; j < 4; ++j)
                Cg[(size_t)(crow0 + m * 16 + j) * N_DIM + ccol0 + n * 16] = acc[m][n][j];
}

extern "C" void kernel_launch(void* const* d_in, const int* in_sizes, int n_in,
                              void* d_out, int out_size, void* d_ws, size_t ws_size,
                              hipStream_t stream) {
    const float* x = (const float*)d_in[0];   // [B, D]
    const float* a = (const float*)d_in[1];   // [C, D]
    float* out = (float*)d_out;               // [B, C]

    const int Bn = in_sizes[0] / D_DIM;  // 16384
    const int Cn = in_sizes[1] / D_DIM;  // 2048

    unsigned short* xn = (unsigned short*)d_ws;            // [B][D] bf16
    unsigned short* an = xn + (size_t)Bn * D_DIM;          // [C][D] bf16

    normalize_rows<<<Bn + Cn, 256, 0, stream>>>(x, a, xn, an, Bn);

    const int grid = (Bn / BMt) * (Cn / BNt);  // 64 * 8 = 512
    gemm256<<<grid, 512, 0, stream>>>(xn, an, out);
}

// Round 8
// 95.631 us; speedup vs baseline: 1.2402x; 1.2402x over previous
//
#include <hip/hip_runtime.h>
#include <stdint.h>

// out[b,c] = <x_b/||x_b||, a_c/||a_c||>, B=16384, C=2048, D=1024, fp32 in/out.
// Pass 1: fp32 row-normalize -> bf16 into d_ws (single merged launch).
// Pass 2: bf16 MFMA GEMM, 256x256 tile, BK=64, **4 waves of 128x128 output**
//   (reads/FLOP 1.5x lower than 8x(128x64): LDS reads 128KB/CU-tile < MFMA
//   floor 2483 cyc), double-buffered LDS (128 KiB), 4 phases/K-tile,
//   prev-phase-consume register pipeline (R6 scheme), counted vmcnt
//   (8/4, never 0 steady), XOR swizzle (0 conflicts), XCD chunked swizzle.
//   Regs: 256 AGPR acc + ~160 VGPR = ~416 unified < 512 -> 1 wave/SIMD, no spill.

#define D_DIM 1024
#define N_DIM 2048
#define BMt 256
#define BNt 256
#define BKt 64
#define NKT 16      // D_DIM / BKt

typedef __bf16 bf16x8 __attribute__((ext_vector_type(8)));
typedef float  f32x4  __attribute__((ext_vector_type(4)));

__device__ __forceinline__ unsigned short f2bf(float f) {
    union { float f; uint32_t u; } v; v.f = f;
    uint32_t r = v.u + 0x7fffu + ((v.u >> 16) & 1u);  // RNE
    return (unsigned short)(r >> 16);
}

// One block per row (X rows then A rows): 256 threads x float4 = 1024 floats.
__global__ __launch_bounds__(256) void normalize_rows(
        const float* __restrict__ x, const float* __restrict__ a,
        unsigned short* __restrict__ xn, unsigned short* __restrict__ an,
        int Bn) {
    const int blk = blockIdx.x;
    const float* in = (blk < Bn) ? x : a;
    unsigned short* out = (blk < Bn) ? xn : an;
    const int row = (blk < Bn) ? blk : blk - Bn;
    const int t = threadIdx.x;
    const float4 v = ((const float4*)(in + (size_t)row * D_DIM))[t];
    float ss = v.x * v.x + v.y * v.y + v.z * v.z + v.w * v.w;
#pragma unroll
    for (int o = 1; o < 64; o <<= 1) ss += __shfl_xor(ss, o);
    __shared__ float red[4];
    if ((t & 63) == 0) red[t >> 6] = ss;
    __syncthreads();
    const float tot = red[0] + red[1] + red[2] + red[3];
    const float scale = 1.0f / fmaxf(sqrtf(tot), 1e-8f);
    ushort4 o;
    o.x = f2bf(v.x * scale);
    o.y = f2bf(v.y * scale);
    o.z = f2bf(v.z * scale);
    o.w = f2bf(v.w * scale);
    ((ushort4*)(out + (size_t)row * D_DIM))[t] = o;
}

__device__ __forceinline__ void gload_lds16(const void* g, void* l) {
    __builtin_amdgcn_global_load_lds(
        (const __attribute__((address_space(1))) void*)g,
        (__attribute__((address_space(3))) void*)l,
        16, 0, 0);
}

// LDS op-tile: [256 rows][64 K] bf16, 128 B/row, 8 x 16B slots/row.
// Stored slot = logical slot ^ (row & 7)  -> ds_read_b128 conflict-free.
__device__ __forceinline__ bf16x8 lds_frag(const unsigned short* opb, int R, int t) {
    const int byt = R * 128 + ((t ^ (R & 7)) << 4);
    return *(const bf16x8*)((const char*)opb + byt);
}

// Stage one half-tile (128 rows x 64 K = 16 KB): 4 gload_lds per thread
// (256 threads). Linear LDS dest; global col pre-swizzled (rule #21).
__device__ __forceinline__ void stage_half(
        const unsigned short* __restrict__ src, int grow0, int k0,
        unsigned short* dst_region, int tid) {
    const int gcol = (((tid & 7) ^ ((tid >> 3) & 7)) << 3);
    const int grow = (tid >> 3);
#pragma unroll
    for (int j = 0; j < 4; ++j)
        gload_lds16(&src[(size_t)(grow0 + j * 32 + grow) * D_DIM + k0 + gcol],
                    dst_region + ((size_t)(j * 256 + tid)) * 8);
}

#define PH_BAR()   asm volatile("s_barrier" ::: "memory")
#define PH_LGKM0() asm volatile("s_waitcnt lgkmcnt(0)" ::: "memory")
#define VMCNT8()   asm volatile("s_waitcnt vmcnt(8)" ::: "memory")
#define VMCNT4()   asm volatile("s_waitcnt vmcnt(4)" ::: "memory")
#define VMCNT0()   asm volatile("s_waitcnt vmcnt(0)" ::: "memory")

// 32-MFMA quadrant: acc[MOFF..MOFF+3][NOFF..NOFF+3] += AF x BF
#define MFMA_Q(AF, BF, MOFF, NOFF)                                            \
    __builtin_amdgcn_s_setprio(1);                                            \
    _Pragma("unroll") for (int m = 0; m < 4; ++m)                             \
    _Pragma("unroll") for (int n = 0; n < 4; ++n)                             \
    _Pragma("unroll") for (int kk = 0; kk < 2; ++kk)                          \
        acc[(MOFF) + m][(NOFF) + n] = __builtin_amdgcn_mfma_f32_16x16x32_bf16(\
            AF[m][kk], BF[n][kk], acc[(MOFF) + m][(NOFF) + n], 0, 0, 0);      \
    __builtin_amdgcn_s_setprio(0);

// Quadrants: Q0(afA,bfN0)@ph0 Q1(afA,bfN1)@ph1 Q2(afB,bfN1)@ph2 Q3(afB,bfN0)@ph3.
// MFMA consumes regs read >=1 phase earlier. Reads per phase: 8/8/8/8.
// Stage schedule: B0(t+1)@ph0, B1(t+1)@ph1, A0(t+2)@ph2, A1(t+2)@ph3.
// Guards (4 loads per half):
//   end-ph1: lgkm0 (A(t)-region reuse) + vmcnt(8) -> ph2 BAR -> read afA'(t+1)
//   end-ph2: vmcnt(4) (B(t+1) halves landed)      -> ph3 BAR -> read bfN0'(t+1)
// MODE 0: t=0..13   MODE 1: t=14 (no A(16) stage; end-ph2 vmcnt(0))
// MODE 2: t=15 (tail: no stages, no read-ahead)
template<int MODE>
__device__ __forceinline__ void ktile(
        int t, const unsigned short* __restrict__ A,
        const unsigned short* __restrict__ Bm, unsigned short* lds,
        int rowA0, int rowB0, int tid, int wr, int wc,
        bf16x8 (&afA)[4][2], bf16x8 (&afB)[4][2],
        bf16x8 (&bfN0)[4][2], bf16x8 (&bfN1)[4][2],
        f32x4 (&acc)[8][8])
{
    const int lane = tid & 63;
    const int rl = lane & 15, ts = lane >> 4;
    unsigned short* bufA = lds + ((size_t)((t & 1) * 2 + 0)) * 16384;       // A(t)
    unsigned short* bufB = lds + ((size_t)((t & 1) * 2 + 1)) * 16384;       // B(t)
    unsigned short* nxA  = lds + ((size_t)(((t + 1) & 1) * 2 + 0)) * 16384; // A(t+1)
    unsigned short* nxB  = lds + ((size_t)(((t + 1) & 1) * 2 + 1)) * 16384; // B(t+1) dst
    unsigned short* stA  = bufA;                                            // A(t+2) dst

    // ---- ph0: read bfN1 (B(t) cols wc*128+64..127); stage B0(t+1); MFMA Q0
    PH_BAR();
#pragma unroll
    for (int n = 0; n < 4; ++n)
#pragma unroll
        for (int kk = 0; kk < 2; ++kk)
            bfN1[n][kk] = lds_frag(bufB, wc * 128 + 64 + n * 16 + rl, kk * 4 + ts);
    if constexpr (MODE <= 1)
        stage_half(Bm, rowB0 + 0, (t + 1) * BKt, nxB + 0, tid);
    MFMA_Q(afA, bfN0, 0, 0)

    // ---- ph1: read afB (A(t) rows wr*128+64..127); stage B1(t+1); MFMA Q1; guards
    PH_BAR();
#pragma unroll
    for (int m = 0; m < 4; ++m)
#pragma unroll
        for (int kk = 0; kk < 2; ++kk)
            afB[m][kk] = lds_frag(bufA, wr * 128 + 64 + m * 16 + rl, kk * 4 + ts);
    if constexpr (MODE <= 1)
        stage_half(Bm, rowB0 + 128, (t + 1) * BKt, nxB + 8192, tid);
    MFMA_Q(afA, bfN1, 0, 4)
    if constexpr (MODE <= 1) {
        PH_LGKM0();   // my A(t)/B(t) ds_reads drained before A(t+2) overwrites bufA
        VMCNT8();     // A(t+1) landed (outstanding: B0',B1' = 8)
    }

    // ---- ph2: stage A0(t+2); MFMA Q2; read afA'(t+1) after; guard B(t+1)
    PH_BAR();
    if constexpr (MODE == 0)
        stage_half(A, rowA0 + 0, (t + 2) * BKt, stA + 0, tid);
    MFMA_Q(afB, bfN1, 4, 4)
    if constexpr (MODE <= 1) {
#pragma unroll
        for (int m = 0; m < 4; ++m)
#pragma unroll
            for (int kk = 0; kk < 2; ++kk)
                afA[m][kk] = lds_frag(nxA, wr * 128 + m * 16 + rl, kk * 4 + ts);
    }
    if constexpr (MODE == 0) VMCNT4();   // B(t+1) landed (leaves A0(t+2))
    if constexpr (MODE == 1) VMCNT0();   // drain B(15)

    // ---- ph3: stage A1(t+2); MFMA Q3; read bfN0'(t+1) after
    PH_BAR();
    if constexpr (MODE == 0)
        stage_half(A, rowA0 + 128, (t + 2) * BKt, stA + 8192, tid);
    MFMA_Q(afB, bfN0, 4, 0)
    if constexpr (MODE <= 1) {
#pragma unroll
        for (int n = 0; n < 4; ++n)
#pragma unroll
            for (int kk = 0; kk < 2; ++kk)
                bfN0[n][kk] = lds_frag(nxB, wc * 128 + n * 16 + rl, kk * 4 + ts);
    }
}

__global__ __launch_bounds__(256, 1) void gemm256(
        const unsigned short* __restrict__ A,
        const unsigned short* __restrict__ Bm,
        float* __restrict__ Cg)
{
    __shared__ unsigned short lds[65536];  // 128 KiB: 4 regions x 32 KB

    const int nwg = gridDim.x;          // 512
    const int cpx = nwg >> 3;           // 64
    const int wg  = ((int)blockIdx.x & 7) * cpx + ((int)blockIdx.x >> 3);
    const int bm  = wg >> 3;            // 0..63
    const int bn  = wg & 7;             // 0..7
    const int rowA0 = bm * BMt;
    const int rowB0 = bn * BNt;

    const int tid  = threadIdx.x;
    const int lane = tid & 63;
    const int wid  = tid >> 6;          // 0..3
    const int wr   = wid >> 1;          // 0..1 -> 128-row half
    const int wc   = wid & 1;           // 0..1 -> 128-col half
    const int rl = lane & 15, ts = lane >> 4;

    bf16x8 afA[4][2], afB[4][2], bfN0[4][2], bfN1[4][2];
    f32x4 acc[8][8] = {};

    // prologue: stage A(0), B(0), A(1); vmcnt(8) -> barrier -> preload afA, bfN0
    {
        unsigned short* r00 = lds + 0;          // A(0)
        unsigned short* r01 = lds + 16384;      // B(0)
        unsigned short* r10 = lds + 32768;      // A(1)
        stage_half(A,  rowA0 + 0,   0,   r00 + 0,    tid);
        stage_half(A,  rowA0 + 128, 0,   r00 + 8192, tid);
        stage_half(Bm, rowB0 + 0,   0,   r01 + 0,    tid);
        stage_half(Bm, rowB0 + 128, 0,   r01 + 8192, tid);
        stage_half(A,  rowA0 + 0,   BKt, r10 + 0,    tid);
        stage_half(A,  rowA0 + 128, BKt, r10 + 8192, tid);
        VMCNT8();
        PH_BAR();
#pragma unroll
        for (int m = 0; m < 4; ++m)
#pragma unroll
            for (int kk = 0; kk < 2; ++kk)
                afA[m][kk] = lds_frag(r00, wr * 128 + m * 16 + rl, kk * 4 + ts);
#pragma unroll
        for (int n = 0; n < 4; ++n)
#pragma unroll
            for (int kk = 0; kk < 2; ++kk)
                bfN0[n][kk] = lds_frag(r01, wc * 128 + n * 16 + rl, kk * 4 + ts);
    }

#pragma unroll 1
    for (int t = 0; t < NKT - 2; ++t)
        ktile<0>(t, A, Bm, lds, rowA0, rowB0, tid, wr, wc, afA, afB, bfN0, bfN1, acc);
    ktile<1>(NKT - 2, A, Bm, lds, rowA0, rowB0, tid, wr, wc, afA, afB, bfN0, bfN1, acc);
    ktile<2>(NKT - 1, A, Bm, lds, rowA0, rowB0, tid, wr, wc, afA, afB, bfN0, bfN1, acc);

    // epilogue: C/D layout col=lane&15, row=(lane>>4)*4+j (m89-verified)
    const int crow0 = rowA0 + wr * 128 + (lane >> 4) * 4;
    const int ccol0 = rowB0 + wc * 128 + (lane & 15);
#pragma unroll
    for (int m = 0; m < 8; ++m)
#pragma unroll
        for (int n = 0; n < 8; ++n)
#pragma unroll
            for (int j = 0; j < 4; ++j)
                Cg[(size_t)(crow0 + m * 16 + j) * N_DIM + ccol0 + n * 16] = acc[m][n][j];
}

extern "C" void kernel_launch(void* const* d_in, const int* in_sizes, int n_in,
                              void* d_out, int out_size, void* d_ws, size_t ws_size,
                              hipStream_t stream) {
    const float* x = (const float*)d_in[0];   // [B, D]
    const float* a = (const float*)d_in[1];   // [C, D]
    float* out = (float*)d_out;               // [B, C]

    const int Bn = in_sizes[0] / D_DIM;  // 16384
    const int Cn = in_sizes[1] / D_DIM;  // 2048

    unsigned short* xn = (unsigned short*)d_ws;            // [B][D] bf16
    unsigned short* an = xn + (size_t)Bn * D_DIM;          // [C][D] bf16

    normalize_rows<<<Bn + Cn, 256, 0, stream>>>(x, a, xn, an, Bn);

    const int grid = (Bn / BMt) * (Cn / BNt);  // 64 * 8 = 512
    gemm256<<<grid, 256, 0, stream>>>(xn, an, out);
}

// Round 9
// 93.366 us; speedup vs baseline: 1.2703x; 1.0243x over previous
//
#include <hip/hip_runtime.h>
#include <stdint.h>

// out[b,c] = <x_b/||x_b||, a_c/||a_c||>, B=16384, C=2048, D=1024, fp32 in/out.
// Pass 1: fp32 row-normalize -> bf16 into d_ws (single merged launch).
// Pass 2: bf16 MFMA GEMM, 256x256 tile, BK=64, 8 waves (2Mx4N), double-buffered
//   LDS (128 KiB), 4 phases/K-tile, prev-phase-consume register pipeline.
//   R9 change vs R6: DEEP PREFETCH (m201 depth). All staging in ph2/ph3:
//   tile t stages A(t+2) then B(t+2) (A-halves before B-halves). Guards:
//     end-ph1: lgkm0 (A(t)/B(t) region reuse) + vmcnt(2)  -> A(t+1) landed,
//              issued 3-4 phases (~2400cyc) earlier >> HBM latency.
//     end-ph2: vmcnt(4) -> B(t+1) landed (leaves A0/B0(t+2) in flight).
//   Every counted wait targets loads >=3 phases old; 2-4 half-tiles stay in
//   flight at all times (never vmcnt(0) in steady state).
//   Race rule: cross-wave LDS read-ahead sits behind a barrier that every
//   wave reaches AFTER its own counted-vmcnt guard (vmcnt -> BAR -> read).

#define D_DIM 1024
#define N_DIM 2048
#define BMt 256
#define BNt 256
#define BKt 64
#define NKT 16      // D_DIM / BKt

typedef __bf16 bf16x8 __attribute__((ext_vector_type(8)));
typedef float  f32x4  __attribute__((ext_vector_type(4)));

__device__ __forceinline__ unsigned short f2bf(float f) {
    union { float f; uint32_t u; } v; v.f = f;
    uint32_t r = v.u + 0x7fffu + ((v.u >> 16) & 1u);  // RNE
    return (unsigned short)(r >> 16);
}

// One block per row (X rows then A rows): 256 threads x float4 = 1024 floats.
__global__ __launch_bounds__(256) void normalize_rows(
        const float* __restrict__ x, const float* __restrict__ a,
        unsigned short* __restrict__ xn, unsigned short* __restrict__ an,
        int Bn) {
    const int blk = blockIdx.x;
    const float* in = (blk < Bn) ? x : a;
    unsigned short* out = (blk < Bn) ? xn : an;
    const int row = (blk < Bn) ? blk : blk - Bn;
    const int t = threadIdx.x;
    const float4 v = ((const float4*)(in + (size_t)row * D_DIM))[t];
    float ss = v.x * v.x + v.y * v.y + v.z * v.z + v.w * v.w;
#pragma unroll
    for (int o = 1; o < 64; o <<= 1) ss += __shfl_xor(ss, o);
    __shared__ float red[4];
    if ((t & 63) == 0) red[t >> 6] = ss;
    __syncthreads();
    const float tot = red[0] + red[1] + red[2] + red[3];
    const float scale = 1.0f / fmaxf(sqrtf(tot), 1e-8f);
    ushort4 o;
    o.x = f2bf(v.x * scale);
    o.y = f2bf(v.y * scale);
    o.z = f2bf(v.z * scale);
    o.w = f2bf(v.w * scale);
    ((ushort4*)(out + (size_t)row * D_DIM))[t] = o;
}

__device__ __forceinline__ void gload_lds16(const void* g, void* l) {
    __builtin_amdgcn_global_load_lds(
        (const __attribute__((address_space(1))) void*)g,
        (__attribute__((address_space(3))) void*)l,
        16, 0, 0);
}

// LDS op-tile: [256 rows][64 K] bf16, 128 B/row, 8 x 16B slots/row.
// Stored slot = logical slot ^ (row & 7)  -> ds_read_b128 conflict-free.
__device__ __forceinline__ bf16x8 lds_frag(const unsigned short* opb, int R, int t) {
    const int byt = R * 128 + ((t ^ (R & 7)) << 4);
    return *(const bf16x8*)((const char*)opb + byt);
}

// Stage one half-tile (128 rows x 64 K = 16 KB): 2 gload_lds per thread
// (512 threads). Linear LDS dest; global col pre-swizzled (rule #21).
__device__ __forceinline__ void stage_half(
        const unsigned short* __restrict__ src, int grow0, int k0,
        unsigned short* dst_region, int tid, int wid) {
    const int gcol = (((tid & 7) ^ ((tid >> 3) & 7)) << 3);
    const int grow = (tid >> 3);
#pragma unroll
    for (int j = 0; j < 2; ++j)
        gload_lds16(&src[(size_t)(grow0 + j * 64 + grow) * D_DIM + k0 + gcol],
                    dst_region + ((size_t)(j * 512 + wid * 64)) * 8);
}

#define PH_BAR()   asm volatile("s_barrier" ::: "memory")
#define PH_LGKM0() asm volatile("s_waitcnt lgkmcnt(0)" ::: "memory")
#define VMCNT8()   asm volatile("s_waitcnt vmcnt(8)" ::: "memory")
#define VMCNT4()   asm volatile("s_waitcnt vmcnt(4)" ::: "memory")
#define VMCNT2()   asm volatile("s_waitcnt vmcnt(2)" ::: "memory")
#define VMCNT0()   asm volatile("s_waitcnt vmcnt(0)" ::: "memory")

// 16-MFMA quadrant: acc[MOFF..MOFF+3][NOFF..NOFF+1] += AF x BF
#define MFMA_Q(AF, BF, MOFF, NOFF)                                            \
    __builtin_amdgcn_s_setprio(1);                                            \
    _Pragma("unroll") for (int m = 0; m < 4; ++m)                             \
    _Pragma("unroll") for (int n = 0; n < 2; ++n)                             \
    _Pragma("unroll") for (int kk = 0; kk < 2; ++kk)                          \
        acc[(MOFF) + m][(NOFF) + n] = __builtin_amdgcn_mfma_f32_16x16x32_bf16(\
            AF[m][kk], BF[n][kk], acc[(MOFF) + m][(NOFF) + n], 0, 0, 0);      \
    __builtin_amdgcn_s_setprio(0);

// Quadrants: Q0(afA,bfN0)@ph0 Q1(afA,bfN1)@ph1 Q2(afB,bfN1)@ph2 Q3(afB,bfN0)@ph3.
// MFMA consumes regs read >=1 phase earlier.
// VM issue order per tile (steady): ph2: A0(t+2),B0(t+2); ph3: A1(t+2),B1(t+2).
// MODE 0: t=0..13   MODE 1: t=14 (no stages; end-ph2 vmcnt(0))
// MODE 2: t=15 (tail: no stages, no read-ahead, no guards)
template<int MODE>
__device__ __forceinline__ void ktile(
        int t, const unsigned short* __restrict__ A,
        const unsigned short* __restrict__ Bm, unsigned short* lds,
        int rowA0, int rowB0, int tid, int wid, int wr, int wc,
        bf16x8 (&afA)[4][2], bf16x8 (&afB)[4][2],
        bf16x8 (&bfN0)[2][2], bf16x8 (&bfN1)[2][2],
        f32x4 (&acc)[8][4])
{
    const int lane = tid & 63;
    const int rl = lane & 15, ts = lane >> 4;
    unsigned short* bufA = lds + ((size_t)((t & 1) * 2 + 0)) * 16384;       // A(t)
    unsigned short* bufB = lds + ((size_t)((t & 1) * 2 + 1)) * 16384;       // B(t)
    unsigned short* nxA  = lds + ((size_t)(((t + 1) & 1) * 2 + 0)) * 16384; // A(t+1)
    unsigned short* nxB  = lds + ((size_t)(((t + 1) & 1) * 2 + 1)) * 16384; // B(t+1)
    unsigned short* stA  = bufA;                                            // A(t+2) dst
    unsigned short* stB  = bufB;                                            // B(t+2) dst

    // ---- ph0: read bfN1 (B(t) N1); MFMA Q0
    PH_BAR();
#pragma unroll
    for (int n = 0; n < 2; ++n)
#pragma unroll
        for (int kk = 0; kk < 2; ++kk)
            bfN1[n][kk] = lds_frag(bufB, wc * 64 + 32 + n * 16 + rl, kk * 4 + ts);
    MFMA_Q(afA, bfN0, 0, 0)

    // ---- ph1: read afB (A(t) M1); MFMA Q1; guards
    PH_BAR();
#pragma unroll
    for (int m = 0; m < 4; ++m)
#pragma unroll
        for (int kk = 0; kk < 2; ++kk)
            afB[m][kk] = lds_frag(bufA, wr * 128 + 64 + m * 16 + rl, kk * 4 + ts);
    MFMA_Q(afA, bfN1, 0, 2)
    if constexpr (MODE == 0) PH_LGKM0();  // A(t)/B(t) region reads drained (restage)
    if constexpr (MODE <= 1) VMCNT2();    // A(t+1) landed (issued t-1 ph2/3)

    // ---- ph2: stage A0(t+2) then B0(t+2); MFMA Q2; read afA'(t+1); guard
    PH_BAR();
    if constexpr (MODE == 0) {
        stage_half(A,  rowA0 + 0, (t + 2) * BKt, stA + 0, tid, wid);
        stage_half(Bm, rowB0 + 0, (t + 2) * BKt, stB + 0, tid, wid);
    }
    MFMA_Q(afB, bfN1, 4, 2)
    if constexpr (MODE <= 1) {
#pragma unroll
        for (int m = 0; m < 4; ++m)
#pragma unroll
            for (int kk = 0; kk < 2; ++kk)
                afA[m][kk] = lds_frag(nxA, wr * 128 + m * 16 + rl, kk * 4 + ts);
    }
    if constexpr (MODE == 0) VMCNT4();   // B(t+1) landed; leaves A0/B0(t+2) in flight
    if constexpr (MODE == 1) VMCNT0();   // drain B(15)

    // ---- ph3: stage A1(t+2) then B1(t+2); MFMA Q3; read bfN0'(t+1)
    PH_BAR();
    if constexpr (MODE == 0) {
        stage_half(A,  rowA0 + 128, (t + 2) * BKt, stA + 8192, tid, wid);
        stage_half(Bm, rowB0 + 128, (t + 2) * BKt, stB + 8192, tid, wid);
    }
    MFMA_Q(afB, bfN0, 4, 0)
    if constexpr (MODE <= 1) {
#pragma unroll
        for (int n = 0; n < 2; ++n)
#pragma unroll
            for (int kk = 0; kk < 2; ++kk)
                bfN0[n][kk] = lds_frag(nxB, wc * 64 + n * 16 + rl, kk * 4 + ts);
    }
}

__global__ __launch_bounds__(512, 2) void gemm256(
        const unsigned short* __restrict__ A,
        const unsigned short* __restrict__ Bm,
        float* __restrict__ Cg)
{
    __shared__ unsigned short lds[65536];  // 128 KiB: 4 regions x 32 KB

    const int nwg = gridDim.x;          // 512
    const int cpx = nwg >> 3;           // 64
    const int wg  = ((int)blockIdx.x & 7) * cpx + ((int)blockIdx.x >> 3);
    const int bm  = wg >> 3;            // 0..63
    const int bn  = wg & 7;             // 0..7
    const int rowA0 = bm * BMt;
    const int rowB0 = bn * BNt;

    const int tid  = threadIdx.x;
    const int lane = tid & 63;
    const int wid  = tid >> 6;          // 0..7
    const int wr   = wid >> 2;          // 0..1 -> 128-row half
    const int wc   = wid & 3;           // 0..3 -> 64-col slice
    const int rl = lane & 15, ts = lane >> 4;

    bf16x8 afA[4][2], afB[4][2], bfN0[2][2], bfN1[2][2];
    f32x4 acc[8][4] = {};

    // prologue: stage A(0),B(0) then A(1),B(1) (16 loads);
    // vmcnt(8) -> A(0),B(0) landed -> BAR -> preload afA, bfN0.
    {
        unsigned short* r0A = lds + 0;          // A(0)
        unsigned short* r0B = lds + 16384;      // B(0)
        unsigned short* r1A = lds + 32768;      // A(1)
        unsigned short* r1B = lds + 49152;      // B(1)
        stage_half(A,  rowA0 + 0,   0,   r0A + 0,    tid, wid);
        stage_half(A,  rowA0 + 128, 0,   r0A + 8192, tid, wid);
        stage_half(Bm, rowB0 + 0,   0,   r0B + 0,    tid, wid);
        stage_half(Bm, rowB0 + 128, 0,   r0B + 8192, tid, wid);
        stage_half(A,  rowA0 + 0,   BKt, r1A + 0,    tid, wid);
        stage_half(Bm, rowB0 + 0,   BKt, r1B + 0,    tid, wid);
        stage_half(A,  rowA0 + 128, BKt, r1A + 8192, tid, wid);
        stage_half(Bm, rowB0 + 128, BKt, r1B + 8192, tid, wid);
        VMCNT8();
        PH_BAR();
#pragma unroll
        for (int m = 0; m < 4; ++m)
#pragma unroll
            for (int kk = 0; kk < 2; ++kk)
                afA[m][kk] = lds_frag(r0A, wr * 128 + m * 16 + rl, kk * 4 + ts);
#pragma unroll
        for (int n = 0; n < 2; ++n)
#pragma unroll
            for (int kk = 0; kk < 2; ++kk)
                bfN0[n][kk] = lds_frag(r0B, wc * 64 + n * 16 + rl, kk * 4 + ts);
    }

#pragma unroll 1
    for (int t = 0; t < NKT - 2; ++t)
        ktile<0>(t, A, Bm, lds, rowA0, rowB0, tid, wid, wr, wc, afA, afB, bfN0, bfN1, acc);
    ktile<1>(NKT - 2, A, Bm, lds, rowA0, rowB0, tid, wid, wr, wc, afA, afB, bfN0, bfN1, acc);
    ktile<2>(NKT - 1, A, Bm, lds, rowA0, rowB0, tid, wid, wr, wc, afA, afB, bfN0, bfN1, acc);

    // epilogue: C/D layout col=lane&15, row=(lane>>4)*4+j (m89-verified)
    const int crow0 = rowA0 + wr * 128 + (lane >> 4) * 4;
    const int ccol0 = rowB0 + wc * 64 + (lane & 15);
#pragma unroll
    for (int m = 0; m < 8; ++m)
#pragma unroll
        for (int n = 0; n < 4; ++n)
#pragma unroll
            for (int j = 0; j < 4; ++j)
                Cg[(size_t)(crow0 + m * 16 + j) * N_DIM + ccol0 + n * 16] = acc[m][n][j];
}

extern "C" void kernel_launch(void* const* d_in, const int* in_sizes, int n_in,
                              void* d_out, int out_size, void* d_ws, size_t ws_size,
                              hipStream_t stream) {
    const float* x = (const float*)d_in[0];   // [B, D]
    const float* a = (const float*)d_in[1];   // [C, D]
    float* out = (float*)d_out;               // [B, C]

    const int Bn = in_sizes[0] / D_DIM;  // 16384
    const int Cn = in_sizes[1] / D_DIM;  // 2048

    unsigned short* xn = (unsigned short*)d_ws;            // [B][D] bf16
    unsigned short* an = xn + (size_t)Bn * D_DIM;          // [C][D] bf16

    normalize_rows<<<Bn + Cn, 256, 0, stream>>>(x, a, xn, an, Bn);

    const int grid = (Bn / BMt) * (Cn / BNt);  // 64 * 8 = 512
    gemm256<<<grid, 512, 0, stream>>>(xn, an, out);
}